// Round 7
// baseline (1074.480 us; speedup 1.0000x reference)
//
#include <hip/hip_runtime.h>

#define BLK 256

// ---------------------------------------------------------------------------
// GCN 1->16->1 collapses to scalar message passing (derivation r0):
//   deg[i]  = 1 + #incoming edges
//   dis[i]  = rsqrt(deg[i])
//   xs[i]   = x[i]*dis[i];  t[i] = xs[i] + sum_{col==i} xs[row]
//   a[i]    = dis[i]*t[i];  g[i] = sum_k relu(a[i]W1[k]+b1[k])W2[k]
//   gs[i]   = g[i]*dis[i];  u[i] = gs[i] + sum_{col==i} gs[row]
//   out[i]  = dis[i]*u[i] + b2
//
// HARNESS CONTRACT (r7 fix): integer inputs arrive as int32 (`const int*`),
// NOT the reference's int64. r5/r6 read edge_index as int64 -> 2x OOB read
// -> GPU page fault -> "Aborted (core dumped)". Edge list = 51.2 MB int32,
// L3-resident; read directly (no repacking) with int4 vector loads.
//
// Scratch: ws0=deg->dis, ws1=t->gs (2*n floats total).
// d_out serves as xs -> u -> out (stream-ordered, same-index in-place).
// ---------------------------------------------------------------------------

__global__ void k_zero(float* __restrict__ p, int n) {
    int i = blockIdx.x * blockDim.x + threadIdx.x;
    if (i < n) p[i] = 0.0f;
}

__global__ void k_deg(const int* __restrict__ col, float* __restrict__ deg, int E) {
    int G = (E + 3) >> 2;
    int stride = gridDim.x * blockDim.x;
    for (int g = blockIdx.x * blockDim.x + threadIdx.x; g < G; g += stride) {
        int e = g << 2;
        if (e + 4 <= E) {
            int4 c = *reinterpret_cast<const int4*>(col + e);
            atomicAdd(&deg[c.x], 1.0f);
            atomicAdd(&deg[c.y], 1.0f);
            atomicAdd(&deg[c.z], 1.0f);
            atomicAdd(&deg[c.w], 1.0f);
        } else {
            for (; e < E; ++e) atomicAdd(&deg[col[e]], 1.0f);
        }
    }
}

__global__ void k_agg(const int* __restrict__ row, const int* __restrict__ col,
                      const float* __restrict__ src, float* __restrict__ dst, int E) {
    int G = (E + 3) >> 2;
    int stride = gridDim.x * blockDim.x;
    for (int g = blockIdx.x * blockDim.x + threadIdx.x; g < G; g += stride) {
        int e = g << 2;
        if (e + 4 <= E) {
            int4 r = *reinterpret_cast<const int4*>(row + e);
            int4 c = *reinterpret_cast<const int4*>(col + e);
            float v0 = src[r.x];
            float v1 = src[r.y];
            float v2 = src[r.z];
            float v3 = src[r.w];
            atomicAdd(&dst[c.x], v0);
            atomicAdd(&dst[c.y], v1);
            atomicAdd(&dst[c.z], v2);
            atomicAdd(&dst[c.w], v3);
        } else {
            for (; e < E; ++e) atomicAdd(&dst[col[e]], src[row[e]]);
        }
    }
}

// dis = rsqrt(deg+1) in place; xs -> d_out; t(self) -> ws1
__global__ void k_node1(const float* __restrict__ x, float* __restrict__ deg_dis,
                        float* __restrict__ xs, float* __restrict__ t, int n) {
    int i = blockIdx.x * blockDim.x + threadIdx.x;
    if (i < n) {
        float d = rsqrtf(deg_dis[i] + 1.0f);        // +1 = self loop
        deg_dis[i] = d;                             // ws0 now holds dis
        float v = x[i] * d;
        xs[i] = v;                                  // d_out = gather source
        t[i]  = v;                                  // ws1 = self-loop term
    }
}

// reads t (ws1), writes gs (ws1, in place) and u-self (d_out, overwrites xs)
__global__ void k_node2(const float* __restrict__ dis, float* __restrict__ t_gs,
                        const float* __restrict__ W1, const float* __restrict__ b1,
                        const float* __restrict__ W2, float* __restrict__ u, int n) {
    int i = blockIdx.x * blockDim.x + threadIdx.x;
    if (i < n) {
        float a = dis[i] * t_gs[i];
        float g = 0.0f;
#pragma unroll
        for (int k = 0; k < 16; ++k) {
            float h = fmaf(a, W1[k], b1[k]);
            h = fmaxf(h, 0.0f);
            g = fmaf(h, W2[k], g);
        }
        float v = g * dis[i];
        t_gs[i] = v;                                // gs (scatter source)
        u[i]    = v;                                // self-loop term in d_out
    }
}

// out = dis*u + b2, in place on d_out
__global__ void k_out(const float* __restrict__ dis, float* __restrict__ u_out,
                      const float* __restrict__ b2, int n) {
    int i = blockIdx.x * blockDim.x + threadIdx.x;
    if (i < n) u_out[i] = fmaf(dis[i], u_out[i], b2[0]);
}

extern "C" void kernel_launch(void* const* d_in, const int* in_sizes, int n_in,
                              void* d_out, int out_size, void* d_ws, size_t ws_size,
                              hipStream_t stream) {
    const float* x   = (const float*)d_in[0];
    const int*   idx = (const int*)d_in[1];   // int64 in reference -> int32 here
    const float* W1  = (const float*)d_in[2];
    const float* b1  = (const float*)d_in[3];
    const float* W2  = (const float*)d_in[4];
    const float* b2  = (const float*)d_in[5];

    int n = in_sizes[0];          // x is [N,1]
    int E = in_sizes[1] / 2;      // edge_index is [2,E]
    const int* row = idx;         // source j
    const int* col = idx + E;     // target i

    float* ws0 = (float*)d_ws;            // deg -> dis
    float* ws1 = ws0 + (size_t)n;         // t -> gs
    float* out = (float*)d_out;           // xs -> u -> out

    int nb = (n + BLK - 1) / BLK;
    int G  = (E + 3) / 4;
    int eb = (G + BLK - 1) / BLK;
    if (eb > 2048) eb = 2048;     // grid-stride caps launch size

    k_zero <<<nb, BLK, 0, stream>>>(ws0, n);   // deg = 0 (+1 folded in k_node1)
    k_deg  <<<eb, BLK, 0, stream>>>(col, ws0, E);
    k_node1<<<nb, BLK, 0, stream>>>(x, ws0, out, ws1, n);
    k_agg  <<<eb, BLK, 0, stream>>>(row, col, out, ws1, E);
    k_node2<<<nb, BLK, 0, stream>>>(ws0, ws1, W1, b1, W2, out, n);
    k_agg  <<<eb, BLK, 0, stream>>>(row, col, ws1, out, E);
    k_out  <<<nb, BLK, 0, stream>>>(ws0, out, b2, n);
}

// Round 8
// 1004.695 us; speedup vs baseline: 1.0695x; 1.0695x over previous
//
#include <hip/hip_runtime.h>

#define BLK 256

// ---------------------------------------------------------------------------
// GCN 1->16->1 collapses to scalar message passing (derivation r0):
//   deg[i]  = 1 + #incoming edges
//   dis[i]  = rsqrt(deg[i])
//   xs[i]   = x[i]*dis[i];  t[i] = xs[i] + sum_{col==i} xs[row]
//   a[i]    = dis[i]*t[i];  g[i] = sum_k relu(a[i]W1[k]+b1[k])W2[k]
//   gs[i]   = g[i]*dis[i];  u[i] = gs[i] + sum_{col==i} gs[row]
//   out[i]  = dis[i]*u[i] + b2
//
// r8 fix (from r7 counters): harness compiles WITHOUT -munsafe-fp-atomics,
// so atomicAdd(float*) was a CAS LOOP -> dependent global round trips ->
// 333us/agg at 0.4% VALUBusy. Switch to native HW atomics:
//   deg:  int atomicAdd          (global_atomic_add_u32, native)
//   aggs: unsafeAtomicAdd(float) (global_atomic_add_f32, no-return)
//
// Scratch: ws0=deg(int)->dis(float), ws1=t->gs (2*n words).
// d_out serves as xs -> u -> out (stream-ordered, same-index in-place).
// ---------------------------------------------------------------------------

__global__ void k_zero(int* __restrict__ p, int n) {
    int i = blockIdx.x * blockDim.x + threadIdx.x;
    if (i < n) p[i] = 0;
}

__global__ void k_deg(const int* __restrict__ col, int* __restrict__ deg, int E) {
    int G = (E + 3) >> 2;
    int stride = gridDim.x * blockDim.x;
    for (int g = blockIdx.x * blockDim.x + threadIdx.x; g < G; g += stride) {
        int e = g << 2;
        if (e + 4 <= E) {
            int4 c = *reinterpret_cast<const int4*>(col + e);
            atomicAdd(&deg[c.x], 1);
            atomicAdd(&deg[c.y], 1);
            atomicAdd(&deg[c.z], 1);
            atomicAdd(&deg[c.w], 1);
        } else {
            for (; e < E; ++e) atomicAdd(&deg[col[e]], 1);
        }
    }
}

__global__ void k_agg(const int* __restrict__ row, const int* __restrict__ col,
                      const float* __restrict__ src, float* __restrict__ dst, int E) {
    int G = (E + 3) >> 2;
    int stride = gridDim.x * blockDim.x;
    for (int g = blockIdx.x * blockDim.x + threadIdx.x; g < G; g += stride) {
        int e = g << 2;
        if (e + 4 <= E) {
            int4 r = *reinterpret_cast<const int4*>(row + e);
            int4 c = *reinterpret_cast<const int4*>(col + e);
            float v0 = src[r.x];
            float v1 = src[r.y];
            float v2 = src[r.z];
            float v3 = src[r.w];
            unsafeAtomicAdd(&dst[c.x], v0);   // HW global_atomic_add_f32
            unsafeAtomicAdd(&dst[c.y], v1);
            unsafeAtomicAdd(&dst[c.z], v2);
            unsafeAtomicAdd(&dst[c.w], v3);
        } else {
            for (; e < E; ++e) unsafeAtomicAdd(&dst[col[e]], src[row[e]]);
        }
    }
}

// dis = rsqrt(deg+1) (int deg -> float dis, same buffer); xs -> d_out; t -> ws1
__global__ void k_node1(const float* __restrict__ x, int* __restrict__ deg_i,
                        float* __restrict__ xs, float* __restrict__ t, int n) {
    int i = blockIdx.x * blockDim.x + threadIdx.x;
    if (i < n) {
        float d = rsqrtf((float)deg_i[i] + 1.0f);   // +1 = self loop
        reinterpret_cast<float*>(deg_i)[i] = d;     // ws0 now holds dis
        float v = x[i] * d;
        xs[i] = v;                                  // d_out = gather source
        t[i]  = v;                                  // ws1 = self-loop term
    }
}

// reads t (ws1), writes gs (ws1, in place) and u-self (d_out, overwrites xs)
__global__ void k_node2(const float* __restrict__ dis, float* __restrict__ t_gs,
                        const float* __restrict__ W1, const float* __restrict__ b1,
                        const float* __restrict__ W2, float* __restrict__ u, int n) {
    int i = blockIdx.x * blockDim.x + threadIdx.x;
    if (i < n) {
        float a = dis[i] * t_gs[i];
        float g = 0.0f;
#pragma unroll
        for (int k = 0; k < 16; ++k) {
            float h = fmaf(a, W1[k], b1[k]);
            h = fmaxf(h, 0.0f);
            g = fmaf(h, W2[k], g);
        }
        float v = g * dis[i];
        t_gs[i] = v;                                // gs (scatter source)
        u[i]    = v;                                // self-loop term in d_out
    }
}

// out = dis*u + b2, in place on d_out
__global__ void k_out(const float* __restrict__ dis, float* __restrict__ u_out,
                      const float* __restrict__ b2, int n) {
    int i = blockIdx.x * blockDim.x + threadIdx.x;
    if (i < n) u_out[i] = fmaf(dis[i], u_out[i], b2[0]);
}

extern "C" void kernel_launch(void* const* d_in, const int* in_sizes, int n_in,
                              void* d_out, int out_size, void* d_ws, size_t ws_size,
                              hipStream_t stream) {
    const float* x   = (const float*)d_in[0];
    const int*   idx = (const int*)d_in[1];   // int64 in reference -> int32 here
    const float* W1  = (const float*)d_in[2];
    const float* b1  = (const float*)d_in[3];
    const float* W2  = (const float*)d_in[4];
    const float* b2  = (const float*)d_in[5];

    int n = in_sizes[0];          // x is [N,1]
    int E = in_sizes[1] / 2;      // edge_index is [2,E]
    const int* row = idx;         // source j
    const int* col = idx + E;     // target i

    int*   ws0i = (int*)d_ws;                 // deg (int) -> dis (float)
    float* ws0f = (float*)d_ws;
    float* ws1  = ws0f + (size_t)n;           // t -> gs
    float* out  = (float*)d_out;              // xs -> u -> out

    int nb = (n + BLK - 1) / BLK;
    int G  = (E + 3) / 4;
    int eb = (G + BLK - 1) / BLK;
    if (eb > 2048) eb = 2048;     // grid-stride caps launch size

    k_zero <<<nb, BLK, 0, stream>>>(ws0i, n);  // deg = 0 (+1 folded in k_node1)
    k_deg  <<<eb, BLK, 0, stream>>>(col, ws0i, E);
    k_node1<<<nb, BLK, 0, stream>>>(x, ws0i, out, ws1, n);
    k_agg  <<<eb, BLK, 0, stream>>>(row, col, out, ws1, E);
    k_node2<<<nb, BLK, 0, stream>>>(ws0f, ws1, W1, b1, W2, out, n);
    k_agg  <<<eb, BLK, 0, stream>>>(row, col, ws1, out, E);
    k_out  <<<nb, BLK, 0, stream>>>(ws0f, out, b2, n);
}

// Round 9
// 302.463 us; speedup vs baseline: 3.5524x; 3.3217x over previous
//
#include <hip/hip_runtime.h>

#define BLK    256
#define NH     1024        // histogram/scatter grid blocks (== SCAN_T)
#define SCAN_T 1024
#define SHIFT  13
#define CHUNK  8192        // nodes per bin = 1<<SHIFT (32 KB LDS accumulator)
#define BPB    64          // agg blocks per bin
#define MAXNB  32

// ---------------------------------------------------------------------------
// GCN 1->16->1 == scalar message passing (derivation r0). r9 structure:
// r7/r8 counters: 6.4M scattered device-scope atomics cap at ~19 G/s
// (333us/agg, WRITE_SIZE = 6.4M x 32B write-through, VALUBusy 0.4%).
// Fix: ZERO global atomics. Bin edges by target node (hist -> scan ->
// scatter, precomputed offsets), then aggregate per-bin in LDS
// (native ds_add_f32), flush contiguous partials, coalesced reduce fused
// with node math. All passes are streaming; edge arrays are L3-resident.
// Fallback to r8 direct-atomic path if ws_size can't hold ~80 MB.
// ---------------------------------------------------------------------------

// ---------- binned path ----------

__global__ void k_hist(const int* __restrict__ col, int* __restrict__ hist,
                       int E, int NB) {
    __shared__ int h[MAXNB];
    for (int j = threadIdx.x; j < NB; j += BLK) h[j] = 0;
    __syncthreads();
    int stride = gridDim.x * blockDim.x;
    for (int e = blockIdx.x * blockDim.x + threadIdx.x; e < E; e += stride)
        atomicAdd(&h[col[e] >> SHIFT], 1);          // LDS atomic (native)
    __syncthreads();
    for (int j = threadIdx.x; j < NB; j += BLK)
        hist[blockIdx.x * NB + j] = h[j];
}

// block p: exclusive scan over hist[0..NH)[p]; totals[p] = column sum
__global__ void k_colscan(const int* __restrict__ hist, int* __restrict__ colOff,
                          int* __restrict__ totals, int NB) {
    __shared__ int lds[SCAN_T];
    int p = blockIdx.x, t = threadIdx.x;
    int v = hist[t * NB + p];
    lds[t] = v;
    __syncthreads();
    for (int off = 1; off < SCAN_T; off <<= 1) {
        int add = (t >= off) ? lds[t - off] : 0;
        __syncthreads();
        lds[t] += add;
        __syncthreads();
    }
    colOff[t * NB + p] = lds[t] - v;                // exclusive
    if (t == SCAN_T - 1) totals[p] = lds[t];
}

__global__ void k_binscan(const int* __restrict__ totals, int* __restrict__ binstart,
                          int NB) {
    if (blockIdx.x == 0 && threadIdx.x == 0) {
        int run = 0;
        for (int p = 0; p < NB; ++p) { binstart[p] = run; run += totals[p]; }
        binstart[NB] = run;
    }
}

// same grid + same grid-stride mapping as k_hist => per-block counts match
__global__ void k_scatter(const int* __restrict__ row, const int* __restrict__ col,
                          const int* __restrict__ colOff, const int* __restrict__ binstart,
                          int* __restrict__ rows, int* __restrict__ colsl,
                          int E, int NB) {
    __shared__ int cur[MAXNB];
    for (int j = threadIdx.x; j < NB; j += BLK)
        cur[j] = binstart[j] + colOff[blockIdx.x * NB + j];
    __syncthreads();
    int stride = gridDim.x * blockDim.x;
    for (int e = blockIdx.x * blockDim.x + threadIdx.x; e < E; e += stride) {
        int c = col[e];
        int p = c >> SHIFT;
        int pos = atomicAdd(&cur[p], 1);            // LDS atomic w/ return
        rows[pos]  = row[e];
        colsl[pos] = c & (CHUNK - 1);
    }
}

// bin p = blockIdx/BPB, slice q = blockIdx%BPB; LDS-accumulate, flush partials
template <bool GATHER>
__global__ void k_bagg(const int* __restrict__ rows, const int* __restrict__ colsl,
                       const int* __restrict__ binstart, const float* __restrict__ src,
                       float* __restrict__ partial) {
    __shared__ float acc[CHUNK];
    int p = blockIdx.x / BPB, q = blockIdx.x % BPB;
    for (int j = threadIdx.x; j < CHUNK; j += BLK) acc[j] = 0.0f;
    __syncthreads();
    int s = binstart[p], t = binstart[p + 1];
    long long len = t - s;
    int lo = s + (int)(len * q / BPB);
    int hi = s + (int)(len * (q + 1) / BPB);
    for (int e = lo + threadIdx.x; e < hi; e += BLK) {
        float v = GATHER ? src[rows[e]] : 1.0f;
        atomicAdd(&acc[colsl[e]], v);               // ds_add_f32 (native LDS)
    }
    __syncthreads();
    float* out = partial + (size_t)blockIdx.x * CHUNK;
    for (int j = threadIdx.x; j < CHUNK; j += BLK) out[j] = acc[j];
}

__device__ __forceinline__ float red_sum(const float* __restrict__ partial, int i) {
    int p = i >> SHIFT, il = i & (CHUNK - 1);
    const float* base = partial + ((size_t)p * BPB) * CHUNK + il;
    float s = 0.0f;
#pragma unroll
    for (int q = 0; q < BPB; ++q) s += base[(size_t)q * CHUNK];
    return s;
}

// deg -> dis; xs -> d_out (gather source); t-self -> ws1
__global__ void k_red_deg_node1(const float* __restrict__ partial, const float* __restrict__ x,
                                float* __restrict__ dis, float* __restrict__ xs,
                                float* __restrict__ tself, int n) {
    int i = blockIdx.x * blockDim.x + threadIdx.x;
    if (i >= n) return;
    float d = rsqrtf(red_sum(partial, i) + 1.0f);   // +1 = self loop
    dis[i] = d;
    float v = x[i] * d;
    xs[i] = v;
    tself[i] = v;
}

// t = ws1 + sum; layer-2 pointwise; gs -> ws1 (gather source); u-self -> d_out
__global__ void k_red_node2(const float* __restrict__ partial, const float* __restrict__ dis,
                            float* __restrict__ t_gs, float* __restrict__ u,
                            const float* __restrict__ W1, const float* __restrict__ b1,
                            const float* __restrict__ W2, int n) {
    int i = blockIdx.x * blockDim.x + threadIdx.x;
    if (i >= n) return;
    float tt = t_gs[i] + red_sum(partial, i);
    float a = dis[i] * tt;
    float g = 0.0f;
#pragma unroll
    for (int k = 0; k < 16; ++k) {
        float h = fmaf(a, W1[k], b1[k]);
        h = fmaxf(h, 0.0f);
        g = fmaf(h, W2[k], g);
    }
    float v = g * dis[i];
    t_gs[i] = v;
    u[i]    = v;
}

// out = dis*(u-self + sum) + b2, in place on d_out
__global__ void k_red_out(const float* __restrict__ partial, const float* __restrict__ dis,
                          float* __restrict__ u_out, const float* __restrict__ b2, int n) {
    int i = blockIdx.x * blockDim.x + threadIdx.x;
    if (i >= n) return;
    float uu = u_out[i] + red_sum(partial, i);
    u_out[i] = fmaf(dis[i], uu, b2[0]);
}

// ---------- fallback path (r8: direct device atomics) ----------

__global__ void k_zero(int* __restrict__ p, int n) {
    int i = blockIdx.x * blockDim.x + threadIdx.x;
    if (i < n) p[i] = 0;
}
__global__ void k_deg(const int* __restrict__ col, int* __restrict__ deg, int E) {
    int stride = gridDim.x * blockDim.x;
    for (int e = blockIdx.x * blockDim.x + threadIdx.x; e < E; e += stride)
        atomicAdd(&deg[col[e]], 1);
}
__global__ void k_agg(const int* __restrict__ row, const int* __restrict__ col,
                      const float* __restrict__ src, float* __restrict__ dst, int E) {
    int stride = gridDim.x * blockDim.x;
    for (int e = blockIdx.x * blockDim.x + threadIdx.x; e < E; e += stride)
        unsafeAtomicAdd(&dst[col[e]], src[row[e]]);
}
__global__ void k_node1(const float* __restrict__ x, int* __restrict__ deg_i,
                        float* __restrict__ xs, float* __restrict__ t, int n) {
    int i = blockIdx.x * blockDim.x + threadIdx.x;
    if (i < n) {
        float d = rsqrtf((float)deg_i[i] + 1.0f);
        reinterpret_cast<float*>(deg_i)[i] = d;
        float v = x[i] * d;
        xs[i] = v;
        t[i]  = v;
    }
}
__global__ void k_node2(const float* __restrict__ dis, float* __restrict__ t_gs,
                        const float* __restrict__ W1, const float* __restrict__ b1,
                        const float* __restrict__ W2, float* __restrict__ u, int n) {
    int i = blockIdx.x * blockDim.x + threadIdx.x;
    if (i < n) {
        float a = dis[i] * t_gs[i];
        float g = 0.0f;
#pragma unroll
        for (int k = 0; k < 16; ++k) {
            float h = fmaf(a, W1[k], b1[k]);
            h = fmaxf(h, 0.0f);
            g = fmaf(h, W2[k], g);
        }
        float v = g * dis[i];
        t_gs[i] = v;
        u[i]    = v;
    }
}
__global__ void k_out(const float* __restrict__ dis, float* __restrict__ u_out,
                      const float* __restrict__ b2, int n) {
    int i = blockIdx.x * blockDim.x + threadIdx.x;
    if (i < n) u_out[i] = fmaf(dis[i], u_out[i], b2[0]);
}

// ---------- launch ----------

extern "C" void kernel_launch(void* const* d_in, const int* in_sizes, int n_in,
                              void* d_out, int out_size, void* d_ws, size_t ws_size,
                              hipStream_t stream) {
    const float* x   = (const float*)d_in[0];
    const int*   idx = (const int*)d_in[1];   // int64 in reference -> int32 here
    const float* W1  = (const float*)d_in[2];
    const float* b1  = (const float*)d_in[3];
    const float* W2  = (const float*)d_in[4];
    const float* b2  = (const float*)d_in[5];

    int n = in_sizes[0];
    int E = in_sizes[1] / 2;
    const int* row = idx;
    const int* col = idx + E;

    int NB = (n + CHUNK - 1) >> SHIFT;

    // workspace carve (4-byte words)
    float* wsf = (float*)d_ws;
    size_t o = 0;
    float* dis      = wsf + o;            o += (size_t)n;
    float* ws1      = wsf + o;            o += (size_t)n;
    int*   hist     = (int*)(wsf + o);    o += (size_t)NH * NB;
    int*   colOff   = (int*)(wsf + o);    o += (size_t)NH * NB;
    int*   totals   = (int*)(wsf + o);    o += (size_t)NB;
    int*   binstart = (int*)(wsf + o);    o += (size_t)NB + 1;
    int*   rows     = (int*)(wsf + o);    o += (size_t)E;
    int*   colsl    = (int*)(wsf + o);    o += (size_t)E;
    float* partial  = wsf + o;            o += (size_t)NB * BPB * CHUNK;
    bool can_bin = (NB <= MAXNB) && (ws_size >= o * 4 + 64);

    float* out = (float*)d_out;           // xs -> u -> out
    int nb = (n + BLK - 1) / BLK;

    if (can_bin) {
        k_hist   <<<NH, BLK,    0, stream>>>(col, hist, E, NB);
        k_colscan<<<NB, SCAN_T, 0, stream>>>(hist, colOff, totals, NB);
        k_binscan<<<1,  64,     0, stream>>>(totals, binstart, NB);
        k_scatter<<<NH, BLK,    0, stream>>>(row, col, colOff, binstart, rows, colsl, E, NB);
        k_bagg<false><<<NB * BPB, BLK, 0, stream>>>(rows, colsl, binstart, nullptr, partial);
        k_red_deg_node1<<<nb, BLK, 0, stream>>>(partial, x, dis, out, ws1, n);
        k_bagg<true> <<<NB * BPB, BLK, 0, stream>>>(rows, colsl, binstart, out, partial);
        k_red_node2  <<<nb, BLK, 0, stream>>>(partial, dis, ws1, out, W1, b1, W2, n);
        k_bagg<true> <<<NB * BPB, BLK, 0, stream>>>(rows, colsl, binstart, ws1, partial);
        k_red_out    <<<nb, BLK, 0, stream>>>(partial, dis, out, b2, n);
    } else {
        int*   ws0i = (int*)d_ws;
        float* ws0f = (float*)d_ws;
        int eb = ((E + 3) / 4 + BLK - 1) / BLK;
        if (eb > 2048) eb = 2048;
        k_zero <<<nb, BLK, 0, stream>>>(ws0i, n);
        k_deg  <<<eb, BLK, 0, stream>>>(col, ws0i, E);
        k_node1<<<nb, BLK, 0, stream>>>(x, ws0i, out, ws1, n);
        k_agg  <<<eb, BLK, 0, stream>>>(row, col, out, ws1, E);
        k_node2<<<nb, BLK, 0, stream>>>(ws0f, ws1, W1, b1, W2, out, n);
        k_agg  <<<eb, BLK, 0, stream>>>(row, col, ws1, out, E);
        k_out  <<<nb, BLK, 0, stream>>>(ws0f, out, b2, n);
    }
}

// Round 10
// 297.566 us; speedup vs baseline: 3.6109x; 1.0165x over previous
//
#include <hip/hip_runtime.h>

#define BLK    256
#define NH     1024        // histogram/scatter grid blocks (== SCAN_T)
#define SCAN_T 1024
#define SHIFT  9
#define CHUNK  512         // nodes per bin = 1<<SHIFT (2 KB LDS accumulator)
#define BPB    8           // agg blocks per bin
#define MAXNB  256

// ---------------------------------------------------------------------------
// GCN 1->16->1 == scalar message passing (derivation r0).
// r9 counters: k_bagg latency-bound (VALUBusy 4.5%, occ 25%) — 32KB LDS
// capped occupancy, and partial traffic = BPB*n*4B = 26.6 MB/pass.
// r10: CHUNK 8192->512 (2KB LDS, occ -> thread-cap), BPB 64->8 (partials
// 26.6->3.2 MB), NB 13->196, blocks 832->1568. Edges packed to ONE int
// (row<<SHIFT | col_low, n < 2^23) halving scatter write + bagg read.
// Zero global atomics anywhere. Fallback to direct-atomic path if ws short.
// ---------------------------------------------------------------------------

// ---------- binned path ----------

__global__ void k_hist(const int* __restrict__ col, int* __restrict__ hist,
                       int E, int NB) {
    __shared__ int h[MAXNB];
    for (int j = threadIdx.x; j < NB; j += BLK) h[j] = 0;
    __syncthreads();
    int stride = gridDim.x * blockDim.x;
    for (int e = blockIdx.x * blockDim.x + threadIdx.x; e < E; e += stride)
        atomicAdd(&h[col[e] >> SHIFT], 1);          // LDS atomic (native)
    __syncthreads();
    for (int j = threadIdx.x; j < NB; j += BLK)
        hist[blockIdx.x * NB + j] = h[j];
}

// block p: exclusive scan over hist[0..NH)[p]; totals[p] = column sum
__global__ void k_colscan(const int* __restrict__ hist, int* __restrict__ colOff,
                          int* __restrict__ totals, int NB) {
    __shared__ int lds[SCAN_T];
    int p = blockIdx.x, t = threadIdx.x;
    int v = hist[t * NB + p];
    lds[t] = v;
    __syncthreads();
    for (int off = 1; off < SCAN_T; off <<= 1) {
        int add = (t >= off) ? lds[t - off] : 0;
        __syncthreads();
        lds[t] += add;
        __syncthreads();
    }
    colOff[t * NB + p] = lds[t] - v;                // exclusive
    if (t == SCAN_T - 1) totals[p] = lds[t];
}

__global__ void k_binscan(const int* __restrict__ totals, int* __restrict__ binstart,
                          int NB) {
    if (blockIdx.x == 0 && threadIdx.x == 0) {
        int run = 0;
        for (int p = 0; p < NB; ++p) { binstart[p] = run; run += totals[p]; }
        binstart[NB] = run;
    }
}

// same grid + same grid-stride mapping as k_hist => per-block quotas match.
// packs edge -> single int: (row << SHIFT) | (col & (CHUNK-1))
__global__ void k_scatter(const int* __restrict__ row, const int* __restrict__ col,
                          const int* __restrict__ colOff, const int* __restrict__ binstart,
                          int* __restrict__ pk, int E, int NB) {
    __shared__ int cur[MAXNB];
    for (int j = threadIdx.x; j < NB; j += BLK)
        cur[j] = binstart[j] + colOff[blockIdx.x * NB + j];
    __syncthreads();
    int stride = gridDim.x * blockDim.x;
    for (int e = blockIdx.x * blockDim.x + threadIdx.x; e < E; e += stride) {
        int c = col[e];
        int p = c >> SHIFT;
        int pos = atomicAdd(&cur[p], 1);            // LDS atomic w/ return
        pk[pos] = (row[e] << SHIFT) | (c & (CHUNK - 1));
    }
}

// bin p = blockIdx/BPB, slice q = blockIdx%BPB; LDS-accumulate, flush partials
template <bool GATHER>
__global__ void k_bagg(const int* __restrict__ pk, const int* __restrict__ binstart,
                       const float* __restrict__ src, float* __restrict__ partial) {
    __shared__ float acc[CHUNK];
    int p = blockIdx.x / BPB, q = blockIdx.x % BPB;
    for (int j = threadIdx.x; j < CHUNK; j += BLK) acc[j] = 0.0f;
    __syncthreads();
    int s = binstart[p], t = binstart[p + 1];
    long long len = t - s;
    int lo = s + (int)(len * q / BPB);
    int hi = s + (int)(len * (q + 1) / BPB);
    for (int e = lo + threadIdx.x; e < hi; e += BLK) {
        int v = pk[e];
        float val = GATHER ? src[((unsigned)v) >> SHIFT] : 1.0f;
        atomicAdd(&acc[v & (CHUNK - 1)], val);      // ds_add_f32 (native LDS)
    }
    __syncthreads();
    float* out = partial + (size_t)blockIdx.x * CHUNK;
    for (int j = threadIdx.x; j < CHUNK; j += BLK) out[j] = acc[j];
}

__device__ __forceinline__ float red_sum(const float* __restrict__ partial, int i) {
    int p = i >> SHIFT, il = i & (CHUNK - 1);
    const float* base = partial + ((size_t)p * BPB) * CHUNK + il;
    float s = 0.0f;
#pragma unroll
    for (int q = 0; q < BPB; ++q) s += base[(size_t)q * CHUNK];
    return s;
}

// deg -> dis; xs -> d_out (gather source); t-self -> ws1
__global__ void k_red_deg_node1(const float* __restrict__ partial, const float* __restrict__ x,
                                float* __restrict__ dis, float* __restrict__ xs,
                                float* __restrict__ tself, int n) {
    int i = blockIdx.x * blockDim.x + threadIdx.x;
    if (i >= n) return;
    float d = rsqrtf(red_sum(partial, i) + 1.0f);   // +1 = self loop
    dis[i] = d;
    float v = x[i] * d;
    xs[i] = v;
    tself[i] = v;
}

// t = ws1 + sum; layer-2 pointwise; gs -> ws1 (gather source); u-self -> d_out
__global__ void k_red_node2(const float* __restrict__ partial, const float* __restrict__ dis,
                            float* __restrict__ t_gs, float* __restrict__ u,
                            const float* __restrict__ W1, const float* __restrict__ b1,
                            const float* __restrict__ W2, int n) {
    int i = blockIdx.x * blockDim.x + threadIdx.x;
    if (i >= n) return;
    float tt = t_gs[i] + red_sum(partial, i);
    float a = dis[i] * tt;
    float g = 0.0f;
#pragma unroll
    for (int k = 0; k < 16; ++k) {
        float h = fmaf(a, W1[k], b1[k]);
        h = fmaxf(h, 0.0f);
        g = fmaf(h, W2[k], g);
    }
    float v = g * dis[i];
    t_gs[i] = v;
    u[i]    = v;
}

// out = dis*(u-self + sum) + b2, in place on d_out
__global__ void k_red_out(const float* __restrict__ partial, const float* __restrict__ dis,
                          float* __restrict__ u_out, const float* __restrict__ b2, int n) {
    int i = blockIdx.x * blockDim.x + threadIdx.x;
    if (i >= n) return;
    float uu = u_out[i] + red_sum(partial, i);
    u_out[i] = fmaf(dis[i], uu, b2[0]);
}

// ---------- fallback path (r8: direct device atomics) ----------

__global__ void k_zero(int* __restrict__ p, int n) {
    int i = blockIdx.x * blockDim.x + threadIdx.x;
    if (i < n) p[i] = 0;
}
__global__ void k_deg(const int* __restrict__ col, int* __restrict__ deg, int E) {
    int stride = gridDim.x * blockDim.x;
    for (int e = blockIdx.x * blockDim.x + threadIdx.x; e < E; e += stride)
        atomicAdd(&deg[col[e]], 1);
}
__global__ void k_agg(const int* __restrict__ row, const int* __restrict__ col,
                      const float* __restrict__ src, float* __restrict__ dst, int E) {
    int stride = gridDim.x * blockDim.x;
    for (int e = blockIdx.x * blockDim.x + threadIdx.x; e < E; e += stride)
        unsafeAtomicAdd(&dst[col[e]], src[row[e]]);
}
__global__ void k_node1(const float* __restrict__ x, int* __restrict__ deg_i,
                        float* __restrict__ xs, float* __restrict__ t, int n) {
    int i = blockIdx.x * blockDim.x + threadIdx.x;
    if (i < n) {
        float d = rsqrtf((float)deg_i[i] + 1.0f);
        reinterpret_cast<float*>(deg_i)[i] = d;
        float v = x[i] * d;
        xs[i] = v;
        t[i]  = v;
    }
}
__global__ void k_node2(const float* __restrict__ dis, float* __restrict__ t_gs,
                        const float* __restrict__ W1, const float* __restrict__ b1,
                        const float* __restrict__ W2, float* __restrict__ u, int n) {
    int i = blockIdx.x * blockDim.x + threadIdx.x;
    if (i < n) {
        float a = dis[i] * t_gs[i];
        float g = 0.0f;
#pragma unroll
        for (int k = 0; k < 16; ++k) {
            float h = fmaf(a, W1[k], b1[k]);
            h = fmaxf(h, 0.0f);
            g = fmaf(h, W2[k], g);
        }
        float v = g * dis[i];
        t_gs[i] = v;
        u[i]    = v;
    }
}
__global__ void k_out(const float* __restrict__ dis, float* __restrict__ u_out,
                      const float* __restrict__ b2, int n) {
    int i = blockIdx.x * blockDim.x + threadIdx.x;
    if (i < n) u_out[i] = fmaf(dis[i], u_out[i], b2[0]);
}

// ---------- launch ----------

extern "C" void kernel_launch(void* const* d_in, const int* in_sizes, int n_in,
                              void* d_out, int out_size, void* d_ws, size_t ws_size,
                              hipStream_t stream) {
    const float* x   = (const float*)d_in[0];
    const int*   idx = (const int*)d_in[1];   // int64 in reference -> int32 here
    const float* W1  = (const float*)d_in[2];
    const float* b1  = (const float*)d_in[3];
    const float* W2  = (const float*)d_in[4];
    const float* b2  = (const float*)d_in[5];

    int n = in_sizes[0];
    int E = in_sizes[1] / 2;
    const int* row = idx;
    const int* col = idx + E;

    int NB = (n + CHUNK - 1) >> SHIFT;

    // workspace carve (4-byte words)
    float* wsf = (float*)d_ws;
    size_t o = 0;
    float* dis      = wsf + o;            o += (size_t)n;
    float* ws1      = wsf + o;            o += (size_t)n;
    int*   hist     = (int*)(wsf + o);    o += (size_t)NH * NB;
    int*   colOff   = (int*)(wsf + o);    o += (size_t)NH * NB;
    int*   totals   = (int*)(wsf + o);    o += (size_t)NB;
    int*   binstart = (int*)(wsf + o);    o += (size_t)NB + 1;
    int*   pk       = (int*)(wsf + o);    o += (size_t)E;
    float* partial  = wsf + o;            o += (size_t)NB * BPB * CHUNK;
    bool can_bin = (NB <= MAXNB) && (ws_size >= o * 4 + 64) &&
                   (n < (1 << (31 - SHIFT)));   // row must fit above SHIFT bits

    float* out = (float*)d_out;           // xs -> u -> out
    int nb = (n + BLK - 1) / BLK;

    if (can_bin) {
        k_hist   <<<NH, BLK,    0, stream>>>(col, hist, E, NB);
        k_colscan<<<NB, SCAN_T, 0, stream>>>(hist, colOff, totals, NB);
        k_binscan<<<1,  64,     0, stream>>>(totals, binstart, NB);
        k_scatter<<<NH, BLK,    0, stream>>>(row, col, colOff, binstart, pk, E, NB);
        k_bagg<false><<<NB * BPB, BLK, 0, stream>>>(pk, binstart, nullptr, partial);
        k_red_deg_node1<<<nb, BLK, 0, stream>>>(partial, x, dis, out, ws1, n);
        k_bagg<true> <<<NB * BPB, BLK, 0, stream>>>(pk, binstart, out, partial);
        k_red_node2  <<<nb, BLK, 0, stream>>>(partial, dis, ws1, out, W1, b1, W2, n);
        k_bagg<true> <<<NB * BPB, BLK, 0, stream>>>(pk, binstart, ws1, partial);
        k_red_out    <<<nb, BLK, 0, stream>>>(partial, dis, out, b2, n);
    } else {
        int*   ws0i = (int*)d_ws;
        float* ws0f = (float*)d_ws;
        int eb = ((E + 3) / 4 + BLK - 1) / BLK;
        if (eb > 2048) eb = 2048;
        k_zero <<<nb, BLK, 0, stream>>>(ws0i, n);
        k_deg  <<<eb, BLK, 0, stream>>>(col, ws0i, E);
        k_node1<<<nb, BLK, 0, stream>>>(x, ws0i, out, ws1, n);
        k_agg  <<<eb, BLK, 0, stream>>>(row, col, out, ws1, E);
        k_node2<<<ws_size ? nb : nb, BLK, 0, stream>>>(ws0f, ws1, W1, b1, W2, out, n);
        k_agg  <<<eb, BLK, 0, stream>>>(row, col, ws1, out, E);
        k_out  <<<nb, BLK, 0, stream>>>(ws0f, out, b2, n);
    }
}

// Round 11
// 273.312 us; speedup vs baseline: 3.9313x; 1.0887x over previous
//
#include <hip/hip_runtime.h>

#define BLK    256
#define NH     512         // histogram/scatter grid blocks (== colscan SCAN_T)
#define SHIFT  11
#define CHUNK  2048        // nodes per bin = 1<<SHIFT (8 KB LDS accumulator)
#define BPB    32          // agg blocks per bin
#define MAXNB  256

// ---------------------------------------------------------------------------
// GCN 1->16->1 == scalar message passing (derivation r0).
// r10 counters: k_scatter 90us, WRITE 137MB for 25.6MB payload (5.3x).
// Cause: open write streams = scatter_blocks x NB = 1024x196 = 200K
// cachelines (12.8MB) > L2 -> eviction before lines fill -> no combining.
// (r9: 13K streams -> combining worked, scatter was cheap; its bagg was the
// bottleneck at 25% occupancy / 32KB LDS.)
// r11: CHUNK=2048/NB=49/NH=512 -> 25K streams (1.6MB, fits L2) AND bagg
// keeps 8KB LDS (thread-capped occupancy). BPB=32 -> 1568 bagg blocks.
// Parallel binscan (was serial 1-thread loop). Zero global atomics.
// ---------------------------------------------------------------------------

// ---------- binned path ----------

__global__ void k_hist(const int* __restrict__ col, int* __restrict__ hist,
                       int E, int NB) {
    __shared__ int h[MAXNB];
    for (int j = threadIdx.x; j < NB; j += BLK) h[j] = 0;
    __syncthreads();
    int stride = gridDim.x * blockDim.x;
    for (int e = blockIdx.x * blockDim.x + threadIdx.x; e < E; e += stride)
        atomicAdd(&h[col[e] >> SHIFT], 1);          // LDS atomic (native)
    __syncthreads();
    for (int j = threadIdx.x; j < NB; j += BLK)
        hist[blockIdx.x * NB + j] = h[j];
}

// block p: exclusive scan over hist[0..NH)[p]; totals[p] = column sum
__global__ void k_colscan(const int* __restrict__ hist, int* __restrict__ colOff,
                          int* __restrict__ totals, int NB) {
    __shared__ int lds[NH];
    int p = blockIdx.x, t = threadIdx.x;
    int v = hist[t * NB + p];
    lds[t] = v;
    __syncthreads();
    for (int off = 1; off < NH; off <<= 1) {
        int add = (t >= off) ? lds[t - off] : 0;
        __syncthreads();
        lds[t] += add;
        __syncthreads();
    }
    colOff[t * NB + p] = lds[t] - v;                // exclusive
    if (t == NH - 1) totals[p] = lds[t];
}

// parallel exclusive scan over NB bin totals (NB <= MAXNB)
__global__ void k_binscan(const int* __restrict__ totals, int* __restrict__ binstart,
                          int NB) {
    __shared__ int lds[MAXNB];
    int t = threadIdx.x;
    int v = (t < NB) ? totals[t] : 0;
    lds[t] = v;
    __syncthreads();
    for (int off = 1; off < MAXNB; off <<= 1) {
        int add = (t >= off) ? lds[t - off] : 0;
        __syncthreads();
        lds[t] += add;
        __syncthreads();
    }
    if (t < NB) binstart[t] = lds[t] - v;
    if (t == NB - 1) binstart[NB] = lds[t];
}

// same grid + same grid-stride mapping as k_hist => per-block quotas match.
// packs edge -> single int: (row << SHIFT) | (col & (CHUNK-1))
__global__ void k_scatter(const int* __restrict__ row, const int* __restrict__ col,
                          const int* __restrict__ colOff, const int* __restrict__ binstart,
                          int* __restrict__ pk, int E, int NB) {
    __shared__ int cur[MAXNB];
    for (int j = threadIdx.x; j < NB; j += BLK)
        cur[j] = binstart[j] + colOff[blockIdx.x * NB + j];
    __syncthreads();
    int stride = gridDim.x * blockDim.x;
    for (int e = blockIdx.x * blockDim.x + threadIdx.x; e < E; e += stride) {
        int c = col[e];
        int p = c >> SHIFT;
        int pos = atomicAdd(&cur[p], 1);            // LDS atomic w/ return
        pk[pos] = (row[e] << SHIFT) | (c & (CHUNK - 1));
    }
}

// bin p = blockIdx/BPB, slice q = blockIdx%BPB; LDS-accumulate, flush partials
template <bool GATHER>
__global__ void __launch_bounds__(BLK)
k_bagg(const int* __restrict__ pk, const int* __restrict__ binstart,
       const float* __restrict__ src, float* __restrict__ partial) {
    __shared__ float acc[CHUNK];
    int p = blockIdx.x / BPB, q = blockIdx.x % BPB;
    for (int j = threadIdx.x; j < CHUNK; j += BLK) acc[j] = 0.0f;
    __syncthreads();
    int s = binstart[p], t = binstart[p + 1];
    long long len = t - s;
    int lo = s + (int)(len * q / BPB);
    int hi = s + (int)(len * (q + 1) / BPB);
    for (int e = lo + threadIdx.x; e < hi; e += BLK) {
        int v = pk[e];
        float val = GATHER ? src[((unsigned)v) >> SHIFT] : 1.0f;
        atomicAdd(&acc[v & (CHUNK - 1)], val);      // ds_add_f32 (native LDS)
    }
    __syncthreads();
    float* out = partial + (size_t)blockIdx.x * CHUNK;
    for (int j = threadIdx.x; j < CHUNK; j += BLK) out[j] = acc[j];
}

__device__ __forceinline__ float red_sum(const float* __restrict__ partial, int i) {
    int p = i >> SHIFT, il = i & (CHUNK - 1);
    const float* base = partial + ((size_t)p * BPB) * CHUNK + il;
    float s = 0.0f;
#pragma unroll
    for (int q = 0; q < BPB; ++q) s += base[(size_t)q * CHUNK];
    return s;
}

// deg -> dis; xs -> d_out (gather source); t-self -> ws1
__global__ void k_red_deg_node1(const float* __restrict__ partial, const float* __restrict__ x,
                                float* __restrict__ dis, float* __restrict__ xs,
                                float* __restrict__ tself, int n) {
    int i = blockIdx.x * blockDim.x + threadIdx.x;
    if (i >= n) return;
    float d = rsqrtf(red_sum(partial, i) + 1.0f);   // +1 = self loop
    dis[i] = d;
    float v = x[i] * d;
    xs[i] = v;
    tself[i] = v;
}

// t = ws1 + sum; layer-2 pointwise; gs -> ws1 (gather source); u-self -> d_out
__global__ void k_red_node2(const float* __restrict__ partial, const float* __restrict__ dis,
                            float* __restrict__ t_gs, float* __restrict__ u,
                            const float* __restrict__ W1, const float* __restrict__ b1,
                            const float* __restrict__ W2, int n) {
    int i = blockIdx.x * blockDim.x + threadIdx.x;
    if (i >= n) return;
    float tt = t_gs[i] + red_sum(partial, i);
    float a = dis[i] * tt;
    float g = 0.0f;
#pragma unroll
    for (int k = 0; k < 16; ++k) {
        float h = fmaf(a, W1[k], b1[k]);
        h = fmaxf(h, 0.0f);
        g = fmaf(h, W2[k], g);
    }
    float v = g * dis[i];
    t_gs[i] = v;
    u[i]    = v;
}

// out = dis*(u-self + sum) + b2, in place on d_out
__global__ void k_red_out(const float* __restrict__ partial, const float* __restrict__ dis,
                          float* __restrict__ u_out, const float* __restrict__ b2, int n) {
    int i = blockIdx.x * blockDim.x + threadIdx.x;
    if (i >= n) return;
    float uu = u_out[i] + red_sum(partial, i);
    u_out[i] = fmaf(dis[i], uu, b2[0]);
}

// ---------- fallback path (r8: direct device atomics) ----------

__global__ void k_zero(int* __restrict__ p, int n) {
    int i = blockIdx.x * blockDim.x + threadIdx.x;
    if (i < n) p[i] = 0;
}
__global__ void k_deg(const int* __restrict__ col, int* __restrict__ deg, int E) {
    int stride = gridDim.x * blockDim.x;
    for (int e = blockIdx.x * blockDim.x + threadIdx.x; e < E; e += stride)
        atomicAdd(&deg[col[e]], 1);
}
__global__ void k_agg(const int* __restrict__ row, const int* __restrict__ col,
                      const float* __restrict__ src, float* __restrict__ dst, int E) {
    int stride = gridDim.x * blockDim.x;
    for (int e = blockIdx.x * blockDim.x + threadIdx.x; e < E; e += stride)
        unsafeAtomicAdd(&dst[col[e]], src[row[e]]);
}
__global__ void k_node1(const float* __restrict__ x, int* __restrict__ deg_i,
                        float* __restrict__ xs, float* __restrict__ t, int n) {
    int i = blockIdx.x * blockDim.x + threadIdx.x;
    if (i < n) {
        float d = rsqrtf((float)deg_i[i] + 1.0f);
        reinterpret_cast<float*>(deg_i)[i] = d;
        float v = x[i] * d;
        xs[i] = v;
        t[i]  = v;
    }
}
__global__ void k_node2(const float* __restrict__ dis, float* __restrict__ t_gs,
                        const float* __restrict__ W1, const float* __restrict__ b1,
                        const float* __restrict__ W2, float* __restrict__ u, int n) {
    int i = blockIdx.x * blockDim.x + threadIdx.x;
    if (i < n) {
        float a = dis[i] * t_gs[i];
        float g = 0.0f;
#pragma unroll
        for (int k = 0; k < 16; ++k) {
            float h = fmaf(a, W1[k], b1[k]);
            h = fmaxf(h, 0.0f);
            g = fmaf(h, W2[k], g);
        }
        float v = g * dis[i];
        t_gs[i] = v;
        u[i]    = v;
    }
}
__global__ void k_out(const float* __restrict__ dis, float* __restrict__ u_out,
                      const float* __restrict__ b2, int n) {
    int i = blockIdx.x * blockDim.x + threadIdx.x;
    if (i < n) u_out[i] = fmaf(dis[i], u_out[i], b2[0]);
}

// ---------- launch ----------

extern "C" void kernel_launch(void* const* d_in, const int* in_sizes, int n_in,
                              void* d_out, int out_size, void* d_ws, size_t ws_size,
                              hipStream_t stream) {
    const float* x   = (const float*)d_in[0];
    const int*   idx = (const int*)d_in[1];   // int64 in reference -> int32 here
    const float* W1  = (const float*)d_in[2];
    const float* b1  = (const float*)d_in[3];
    const float* W2  = (const float*)d_in[4];
    const float* b2  = (const float*)d_in[5];

    int n = in_sizes[0];
    int E = in_sizes[1] / 2;
    const int* row = idx;
    const int* col = idx + E;

    int NB = (n + CHUNK - 1) >> SHIFT;

    // workspace carve (4-byte words)
    float* wsf = (float*)d_ws;
    size_t o = 0;
    float* dis      = wsf + o;            o += (size_t)n;
    float* ws1      = wsf + o;            o += (size_t)n;
    int*   hist     = (int*)(wsf + o);    o += (size_t)NH * NB;
    int*   colOff   = (int*)(wsf + o);    o += (size_t)NH * NB;
    int*   totals   = (int*)(wsf + o);    o += (size_t)NB;
    int*   binstart = (int*)(wsf + o);    o += (size_t)NB + 1;
    int*   pk       = (int*)(wsf + o);    o += (size_t)E;
    float* partial  = wsf + o;            o += (size_t)NB * BPB * CHUNK;
    bool can_bin = (NB <= MAXNB) && (ws_size >= o * 4 + 64) &&
                   (n < (1 << (31 - SHIFT)));   // row must fit above SHIFT bits

    float* out = (float*)d_out;           // xs -> u -> out
    int nb = (n + BLK - 1) / BLK;

    if (can_bin) {
        k_hist   <<<NH, BLK,   0, stream>>>(col, hist, E, NB);
        k_colscan<<<NB, NH,    0, stream>>>(hist, colOff, totals, NB);
        k_binscan<<<1,  MAXNB, 0, stream>>>(totals, binstart, NB);
        k_scatter<<<NH, BLK,   0, stream>>>(row, col, colOff, binstart, pk, E, NB);
        k_bagg<false><<<NB * BPB, BLK, 0, stream>>>(pk, binstart, nullptr, partial);
        k_red_deg_node1<<<nb, BLK, 0, stream>>>(partial, x, dis, out, ws1, n);
        k_bagg<true> <<<NB * BPB, BLK, 0, stream>>>(pk, binstart, out, partial);
        k_red_node2  <<<nb, BLK, 0, stream>>>(partial, dis, ws1, out, W1, b1, W2, n);
        k_bagg<true> <<<NB * BPB, BLK, 0, stream>>>(pk, binstart, ws1, partial);
        k_red_out    <<<nb, BLK, 0, stream>>>(partial, dis, out, b2, n);
    } else {
        int*   ws0i = (int*)d_ws;
        float* ws0f = (float*)d_ws;
        int eb = ((E + 3) / 4 + BLK - 1) / BLK;
        if (eb > 2048) eb = 2048;
        k_zero <<<nb, BLK, 0, stream>>>(ws0i, n);
        k_deg  <<<eb, BLK, 0, stream>>>(col, ws0i, E);
        k_node1<<<nb, BLK, 0, stream>>>(x, ws0i, out, ws1, n);
        k_agg  <<<eb, BLK, 0, stream>>>(row, col, out, ws1, E);
        k_node2<<<nb, BLK, 0, stream>>>(ws0f, ws1, W1, b1, W2, out, n);
        k_agg  <<<eb, BLK, 0, stream>>>(row, col, ws1, out, E);
        k_out  <<<nb, BLK, 0, stream>>>(ws0f, out, b2, n);
    }
}

// Round 13
// 251.184 us; speedup vs baseline: 4.2777x; 1.0881x over previous
//
#include <hip/hip_runtime.h>

#define BLK    256
#define NH     1024        // histogram/scatter grid blocks (== colscan threads)
#define SHIFT  11
#define CHUNK  2048        // nodes per bin = 1<<SHIFT (8 KB LDS accumulator)
#define BPB    32          // agg blocks per bin
#define MAXNB  256

// ---------------------------------------------------------------------------
// GCN 1->16->1 == scalar message passing (derivation r0).
// r11 counters: scatter WRITE amplification fixed (25.7MB = payload), but
// scatter still #1 at 50us: VALUBusy 3%, Occupancy 18% -> parallelism-
// starved (512 blocks = 25% wave cap) + serial LDS-atomic-return chain.
// r12/r13: NH 512->1024 (occ cap 25%->50%; per-XCD open streams 128blk*
// 49bin*64B ~ 400KB << 4MB L2, combining preserved), int4 edge loads in
// hist/scatter (4 independent atomics/iter = ILP), 2-way ILP in bagg.
// can_bin additionally requires E%4==0 (int4 alignment of col = idx+E).
// Zero global atomics. Fallback to direct-atomic path otherwise.
// ---------------------------------------------------------------------------

// ---------- binned path ----------

__global__ void k_hist(const int* __restrict__ col, int* __restrict__ hist,
                       int E, int NB) {
    __shared__ int h[MAXNB];
    for (int j = threadIdx.x; j < NB; j += BLK) h[j] = 0;
    __syncthreads();
    int G = E >> 2;
    int stride = gridDim.x * blockDim.x;
    for (int g = blockIdx.x * blockDim.x + threadIdx.x; g < G; g += stride) {
        int4 c = reinterpret_cast<const int4*>(col)[g];
        atomicAdd(&h[c.x >> SHIFT], 1);
        atomicAdd(&h[c.y >> SHIFT], 1);
        atomicAdd(&h[c.z >> SHIFT], 1);
        atomicAdd(&h[c.w >> SHIFT], 1);
    }
    __syncthreads();
    for (int j = threadIdx.x; j < NB; j += BLK)
        hist[blockIdx.x * NB + j] = h[j];
}

// block p: exclusive scan over hist[0..NH)[p]; totals[p] = column sum
__global__ void k_colscan(const int* __restrict__ hist, int* __restrict__ colOff,
                          int* __restrict__ totals, int NB) {
    __shared__ int lds[NH];
    int p = blockIdx.x, t = threadIdx.x;
    int v = hist[t * NB + p];
    lds[t] = v;
    __syncthreads();
    for (int off = 1; off < NH; off <<= 1) {
        int add = (t >= off) ? lds[t - off] : 0;
        __syncthreads();
        lds[t] += add;
        __syncthreads();
    }
    colOff[t * NB + p] = lds[t] - v;                // exclusive
    if (t == NH - 1) totals[p] = lds[t];
}

// parallel exclusive scan over NB bin totals (NB <= MAXNB)
__global__ void k_binscan(const int* __restrict__ totals, int* __restrict__ binstart,
                          int NB) {
    __shared__ int lds[MAXNB];
    int t = threadIdx.x;
    int v = (t < NB) ? totals[t] : 0;
    lds[t] = v;
    __syncthreads();
    for (int off = 1; off < MAXNB; off <<= 1) {
        int add = (t >= off) ? lds[t - off] : 0;
        __syncthreads();
        lds[t] += add;
        __syncthreads();
    }
    if (t < NB) binstart[t] = lds[t] - v;
    if (t == NB - 1) binstart[NB] = lds[t];
}

// same grid + same traversal as k_hist => per-block quotas match.
// packs edge -> single int: (row << SHIFT) | (col & (CHUNK-1))
__global__ void k_scatter(const int* __restrict__ row, const int* __restrict__ col,
                          const int* __restrict__ colOff, const int* __restrict__ binstart,
                          int* __restrict__ pk, int E, int NB) {
    __shared__ int cur[MAXNB];
    for (int j = threadIdx.x; j < NB; j += BLK)
        cur[j] = binstart[j] + colOff[blockIdx.x * NB + j];
    __syncthreads();
    int G = E >> 2;
    int stride = gridDim.x * blockDim.x;
    for (int g = blockIdx.x * blockDim.x + threadIdx.x; g < G; g += stride) {
        int4 r = reinterpret_cast<const int4*>(row)[g];
        int4 c = reinterpret_cast<const int4*>(col)[g];
        int p0 = atomicAdd(&cur[c.x >> SHIFT], 1);
        int p1 = atomicAdd(&cur[c.y >> SHIFT], 1);
        int p2 = atomicAdd(&cur[c.z >> SHIFT], 1);
        int p3 = atomicAdd(&cur[c.w >> SHIFT], 1);
        pk[p0] = (r.x << SHIFT) | (c.x & (CHUNK - 1));
        pk[p1] = (r.y << SHIFT) | (c.y & (CHUNK - 1));
        pk[p2] = (r.z << SHIFT) | (c.z & (CHUNK - 1));
        pk[p3] = (r.w << SHIFT) | (c.w & (CHUNK - 1));
    }
}

// bin p = blockIdx/BPB, slice q = blockIdx%BPB; LDS-accumulate, flush partials
template <bool GATHER>
__global__ void __launch_bounds__(BLK)
k_bagg(const int* __restrict__ pk, const int* __restrict__ binstart,
       const float* __restrict__ src, float* __restrict__ partial) {
    __shared__ float acc[CHUNK];
    int p = blockIdx.x / BPB, q = blockIdx.x % BPB;
    for (int j = threadIdx.x; j < CHUNK; j += BLK) acc[j] = 0.0f;
    __syncthreads();
    int s = binstart[p], t = binstart[p + 1];
    long long len = t - s;
    int lo = s + (int)(len * q / BPB);
    int hi = s + (int)(len * (q + 1) / BPB);
    for (int e = lo + threadIdx.x; e < hi; e += 2 * BLK) {
        int v0 = pk[e];
        int e1 = e + BLK;
        int v1 = (e1 < hi) ? pk[e1] : 0;
        float a0 = GATHER ? src[((unsigned)v0) >> SHIFT] : 1.0f;
        atomicAdd(&acc[v0 & (CHUNK - 1)], a0);      // ds_add_f32 (native LDS)
        if (e1 < hi) {
            float a1 = GATHER ? src[((unsigned)v1) >> SHIFT] : 1.0f;
            atomicAdd(&acc[v1 & (CHUNK - 1)], a1);
        }
    }
    __syncthreads();
    float* out = partial + (size_t)blockIdx.x * CHUNK;
    for (int j = threadIdx.x; j < CHUNK; j += BLK) out[j] = acc[j];
}

__device__ __forceinline__ float red_sum(const float* __restrict__ partial, int i) {
    int p = i >> SHIFT, il = i & (CHUNK - 1);
    const float* base = partial + ((size_t)p * BPB) * CHUNK + il;
    float s = 0.0f;
#pragma unroll
    for (int q = 0; q < BPB; ++q) s += base[(size_t)q * CHUNK];
    return s;
}

// deg -> dis; xs -> d_out (gather source); t-self -> ws1
__global__ void k_red_deg_node1(const float* __restrict__ partial, const float* __restrict__ x,
                                float* __restrict__ dis, float* __restrict__ xs,
                                float* __restrict__ tself, int n) {
    int i = blockIdx.x * blockDim.x + threadIdx.x;
    if (i >= n) return;
    float d = rsqrtf(red_sum(partial, i) + 1.0f);   // +1 = self loop
    dis[i] = d;
    float v = x[i] * d;
    xs[i] = v;
    tself[i] = v;
}

// t = ws1 + sum; layer-2 pointwise; gs -> ws1 (gather source); u-self -> d_out
__global__ void k_red_node2(const float* __restrict__ partial, const float* __restrict__ dis,
                            float* __restrict__ t_gs, float* __restrict__ u,
                            const float* __restrict__ W1, const float* __restrict__ b1,
                            const float* __restrict__ W2, int n) {
    int i = blockIdx.x * blockDim.x + threadIdx.x;
    if (i >= n) return;
    float tt = t_gs[i] + red_sum(partial, i);
    float a = dis[i] * tt;
    float g = 0.0f;
#pragma unroll
    for (int k = 0; k < 16; ++k) {
        float h = fmaf(a, W1[k], b1[k]);
        h = fmaxf(h, 0.0f);
        g = fmaf(h, W2[k], g);
    }
    float v = g * dis[i];
    t_gs[i] = v;
    u[i]    = v;
}

// out = dis*(u-self + sum) + b2, in place on d_out
__global__ void k_red_out(const float* __restrict__ partial, const float* __restrict__ dis,
                          float* __restrict__ u_out, const float* __restrict__ b2, int n) {
    int i = blockIdx.x * blockDim.x + threadIdx.x;
    if (i >= n) return;
    float uu = u_out[i] + red_sum(partial, i);
    u_out[i] = fmaf(dis[i], uu, b2[0]);
}

// ---------- fallback path (r8: direct device atomics) ----------

__global__ void k_zero(int* __restrict__ p, int n) {
    int i = blockIdx.x * blockDim.x + threadIdx.x;
    if (i < n) p[i] = 0;
}
__global__ void k_deg(const int* __restrict__ col, int* __restrict__ deg, int E) {
    int stride = gridDim.x * blockDim.x;
    for (int e = blockIdx.x * blockDim.x + threadIdx.x; e < E; e += stride)
        atomicAdd(&deg[col[e]], 1);
}
__global__ void k_agg(const int* __restrict__ row, const int* __restrict__ col,
                      const float* __restrict__ src, float* __restrict__ dst, int E) {
    int stride = gridDim.x * blockDim.x;
    for (int e = blockIdx.x * blockDim.x + threadIdx.x; e < E; e += stride)
        unsafeAtomicAdd(&dst[col[e]], src[row[e]]);
}
__global__ void k_node1(const float* __restrict__ x, int* __restrict__ deg_i,
                        float* __restrict__ xs, float* __restrict__ t, int n) {
    int i = blockIdx.x * blockDim.x + threadIdx.x;
    if (i < n) {
        float d = rsqrtf((float)deg_i[i] + 1.0f);
        reinterpret_cast<float*>(deg_i)[i] = d;
        float v = x[i] * d;
        xs[i] = v;
        t[i]  = v;
    }
}
__global__ void k_node2(const float* __restrict__ dis, float* __restrict__ t_gs,
                        const float* __restrict__ W1, const float* __restrict__ b1,
                        const float* __restrict__ W2, float* __restrict__ u, int n) {
    int i = blockIdx.x * blockDim.x + threadIdx.x;
    if (i < n) {
        float a = dis[i] * t_gs[i];
        float g = 0.0f;
#pragma unroll
        for (int k = 0; k < 16; ++k) {
            float h = fmaf(a, W1[k], b1[k]);
            h = fmaxf(h, 0.0f);
            g = fmaf(h, W2[k], g);
        }
        float v = g * dis[i];
        t_gs[i] = v;
        u[i]    = v;
    }
}
__global__ void k_out(const float* __restrict__ dis, float* __restrict__ u_out,
                      const float* __restrict__ b2, int n) {
    int i = blockIdx.x * blockDim.x + threadIdx.x;
    if (i < n) u_out[i] = fmaf(dis[i], u_out[i], b2[0]);
}

// ---------- launch ----------

extern "C" void kernel_launch(void* const* d_in, const int* in_sizes, int n_in,
                              void* d_out, int out_size, void* d_ws, size_t ws_size,
                              hipStream_t stream) {
    const float* x   = (const float*)d_in[0];
    const int*   idx = (const int*)d_in[1];   // int64 in reference -> int32 here
    const float* W1  = (const float*)d_in[2];
    const float* b1  = (const float*)d_in[3];
    const float* W2  = (const float*)d_in[4];
    const float* b2  = (const float*)d_in[5];

    int n = in_sizes[0];
    int E = in_sizes[1] / 2;
    const int* row = idx;
    const int* col = idx + E;

    int NB = (n + CHUNK - 1) >> SHIFT;

    // workspace carve (4-byte words)
    float* wsf = (float*)d_ws;
    size_t o = 0;
    float* dis      = wsf + o;            o += (size_t)n;
    float* ws1      = wsf + o;            o += (size_t)n;
    int*   hist     = (int*)(wsf + o);    o += (size_t)NH * NB;
    int*   colOff   = (int*)(wsf + o);    o += (size_t)NH * NB;
    int*   totals   = (int*)(wsf + o);    o += (size_t)NB;
    int*   binstart = (int*)(wsf + o);    o += (size_t)NB + 1;
    int*   pk       = (int*)(wsf + o);    o += (size_t)E;
    float* partial  = wsf + o;            o += (size_t)NB * BPB * CHUNK;
    bool can_bin = (NB <= MAXNB) && (ws_size >= o * 4 + 64) &&
                   (n < (1 << (31 - SHIFT))) &&   // row fits above SHIFT bits
                   ((E & 3) == 0);                // int4 alignment of col=idx+E

    float* out = (float*)d_out;           // xs -> u -> out
    int nb = (n + BLK - 1) / BLK;

    if (can_bin) {
        k_hist   <<<NH, BLK,   0, stream>>>(col, hist, E, NB);
        k_colscan<<<NB, NH,    0, stream>>>(hist, colOff, totals, NB);
        k_binscan<<<1,  MAXNB, 0, stream>>>(totals, binstart, NB);
        k_scatter<<<NH, BLK,   0, stream>>>(row, col, colOff, binstart, pk, E, NB);
        k_bagg<false><<<NB * BPB, BLK, 0, stream>>>(pk, binstart, nullptr, partial);
        k_red_deg_node1<<<nb, BLK, 0, stream>>>(partial, x, dis, out, ws1, n);
        k_bagg<true> <<<NB * BPB, BLK, 0, stream>>>(pk, binstart, out, partial);
        k_red_node2  <<<nb, BLK, 0, stream>>>(partial, dis, ws1, out, W1, b1, W2, n);
        k_bagg<true> <<<NB * BPB, BLK, 0, stream>>>(pk, binstart, ws1, partial);
        k_red_out    <<<nb, BLK, 0, stream>>>(partial, dis, out, b2, n);
    } else {
        int*   ws0i = (int*)d_ws;
        float* ws0f = (float*)d_ws;
        int eb = ((E + 3) / 4 + BLK - 1) / BLK;
        if (eb > 2048) eb = 2048;
        k_zero <<<nb, BLK, 0, stream>>>(ws0i, n);
        k_deg  <<<eb, BLK, 0, stream>>>(col, ws0i, E);
        k_node1<<<nb, BLK, 0, stream>>>(x, ws0i, out, ws1, n);
        k_agg  <<<eb, BLK, 0, stream>>>(row, col, out, ws1, E);
        k_node2<<<nb, BLK, 0, stream>>>(ws0f, ws1, W1, b1, W2, out, n);
        k_agg  <<<eb, BLK, 0, stream>>>(row, col, ws1, out, E);
        k_out  <<<nb, BLK, 0, stream>>>(ws0f, out, b2, n);
    }
}